// Round 4
// baseline (58.697 us; speedup 1.0000x reference)
//
#include <hip/hip_runtime.h>
#include <hip/hip_bf16.h>
#include <math.h>

// inputs: [B=64, I=2048, P=16] f32
// W:      [I=2048, J=32, P=16, D=32] f32
// bias:   [1, I, J, 1, 1] f32
// out:    [B=64, J=32, D=32] f32
#define I_CAP 2048
#define P_DIM 16
#define J_CAP 32
#define D_DIM 32
#define B_SZ  64

typedef __attribute__((ext_vector_type(8)))  short short8_t;
typedef __attribute__((ext_vector_type(16))) float f32x16;

__device__ __forceinline__ short f2bf(float f) {
    __hip_bfloat16 h = __float2bfloat16(f);   // RNE
    return __builtin_bit_cast(short, h);
}

// ---------------- k0: c[i][j] = softmax over j of bias[i][j] ----------------
__global__ __launch_bounds__(256) void caps_softmax_k(const float* __restrict__ bias,
                                                      float* __restrict__ c_tab) {
    int tid = blockIdx.x * 256 + threadIdx.x;   // = i*32 + j
    float x = bias[tid];
    float m = x;
#pragma unroll
    for (int k = 16; k >= 1; k >>= 1) m = fmaxf(m, __shfl_xor(m, k));
    float e = expf(x - m);
    float s = e;
#pragma unroll
    for (int k = 16; k >= 1; k >>= 1) s += __shfl_xor(s, k);
    c_tab[tid] = e / s;
}

// ---------------- k1: main GEMM via bf16 MFMA, partials out (no atomics) ------
// grid = KCN*32 blocks; block (kc = bid>>5, j = bid&31); 4 waves on disjoint i.
// One 32x32x16 MFMA k-step == one (i,j): B = c*W[i,j,:,:], A = inputs[:,i,:].
// B-frag: lane l -> n=d=(l&31), k=p=(l>>5)*8+e   (k-permutation-safe: A uses same map)
// A-frag: lane l -> m=b=(l&31)+32*mf, k=p=(l>>5)*8+e  -> 8 consecutive fp32
// C/D:    b = mf*32 + (reg&3) + 8*(reg>>2) + 4*(l>>5), d = l&31   [m74/m101]
// __launch_bounds__(256,4): 4 waves/SIMD -> 16 waves/CU resident (<=128 VGPR).
template<int IPW_T>
__global__ __launch_bounds__(256, 4) void caps_main_k(const float* __restrict__ inputs,
                                                      const float* __restrict__ W,
                                                      const float* __restrict__ c_tab,
                                                      float* __restrict__ partial) {
    __shared__ float red[4 * 2048];   // 32 KB: per-wave [64 b][32 d]
    const int t  = threadIdx.x;
    const int l  = t & 63;
    const int wv = t >> 6;
    const int j  = blockIdx.x & 31;
    const int kc = blockIdx.x >> 5;
    const int g  = l >> 5;     // p-half selector (k-group)
    const int dn = l & 31;     // d for B-frag, b for A-frag

    const int i0 = kc * (4 * IPW_T) + wv * IPW_T;

    const float* wlane  = W + (((size_t)(i0 * J_CAP + j)) << 9) + g * 256 + dn;
    const float* alane0 = inputs + ((size_t)dn << 15) + (size_t)i0 * 16 + g * 8;
    const float* alane1 = alane0 + ((size_t)32 << 15);
    const float* cp     = c_tab + i0 * J_CAP + j;

    f32x16 acc0 = {};
    f32x16 acc1 = {};

#pragma unroll 2
    for (int r = 0; r < IPW_T; ++r) {
        const float cj = cp[r * J_CAP];                 // wave-uniform
        float wbuf[8];
#pragma unroll
        for (int e = 0; e < 8; ++e)
            wbuf[e] = wlane[(size_t)r * 16384 + e * 32];  // 2x128B lines per inst

        float4 a0 = *(const float4*)(alane0 + r * 16);
        float4 a1 = *(const float4*)(alane0 + r * 16 + 4);
        float4 a2 = *(const float4*)(alane1 + r * 16);
        float4 a3 = *(const float4*)(alane1 + r * 16 + 4);

        short8_t bf, af0, af1;
#pragma unroll
        for (int e = 0; e < 8; ++e) bf[e] = f2bf(wbuf[e] * cj);   // fold c into B
        af0[0] = f2bf(a0.x); af0[1] = f2bf(a0.y); af0[2] = f2bf(a0.z); af0[3] = f2bf(a0.w);
        af0[4] = f2bf(a1.x); af0[5] = f2bf(a1.y); af0[6] = f2bf(a1.z); af0[7] = f2bf(a1.w);
        af1[0] = f2bf(a2.x); af1[1] = f2bf(a2.y); af1[2] = f2bf(a2.z); af1[3] = f2bf(a2.w);
        af1[4] = f2bf(a3.x); af1[5] = f2bf(a3.y); af1[6] = f2bf(a3.z); af1[7] = f2bf(a3.w);

        acc0 = __builtin_amdgcn_mfma_f32_32x32x16_bf16(af0, bf, acc0, 0, 0, 0);
        acc1 = __builtin_amdgcn_mfma_f32_32x32x16_bf16(af1, bf, acc1, 0, 0, 0);
    }

    // ---- epilogue: per-wave C -> LDS (conflict-free), 4-wave sum, partial write --
    {
        float* rw = red + wv * 2048;
#pragma unroll
        for (int reg = 0; reg < 16; ++reg) {
            const int b0 = (reg & 3) + 8 * (reg >> 2) + 4 * g;
            rw[b0 * 32 + dn]        = acc0[reg];
            rw[(b0 + 32) * 32 + dn] = acc1[reg];
        }
    }
    __syncthreads();
    {
        float* dst = partial + (size_t)blockIdx.x * 2048;
#pragma unroll
        for (int s = 0; s < 2; ++s) {
            const int o = s * 1024 + t * 4;
            float4 v0 = *(const float4*)(red + o);
            float4 v1 = *(const float4*)(red + 2048 + o);
            float4 v2 = *(const float4*)(red + 4096 + o);
            float4 v3 = *(const float4*)(red + 6144 + o);
            float4 sum = {v0.x + v1.x + v2.x + v3.x,
                          v0.y + v1.y + v2.y + v3.y,
                          v0.z + v1.z + v2.z + v3.z,
                          v0.w + v1.w + v2.w + v3.w};
            *(float4*)(dst + o) = sum;
        }
    }
}

// ---------------- k2: reduce KCN partials + squash ----------------
// grid = 256 blocks x 256 thr; block -> (j = bid>>3, bgroup = bid&7);
// thread -> (b = bg*8 + t>>5, d = t&31). partial layout: [kc*32+j][b*32+d].
__global__ __launch_bounds__(256) void caps_reduce_squash_k(const float* __restrict__ partial,
                                                            float* __restrict__ out, int kcn) {
    const int t  = threadIdx.x;
    const int j  = blockIdx.x >> 3;
    const int bg = blockIdx.x & 7;
    const int b  = bg * 8 + (t >> 5);
    const int d  = t & 31;

    const float* src = partial + (size_t)j * 2048 + (size_t)b * 32 + d;
    float v = 0.f;
    for (int kc = 0; kc < kcn; ++kc)
        v += src[(size_t)kc * 32 * 2048];

    float sq = v * v;
#pragma unroll
    for (int k = 16; k >= 1; k >>= 1) sq += __shfl_xor(sq, k);
    // scale = s2 / (1+s2) / sqrt(s2)  (exactly as reference)
    float scale = sq / (1.0f + sq) / sqrtf(sq);
    out[(size_t)b * (J_CAP * D_DIM) + j * D_DIM + d] = v * scale;
}

extern "C" void kernel_launch(void* const* d_in, const int* in_sizes, int n_in,
                              void* d_out, int out_size, void* d_ws, size_t ws_size,
                              hipStream_t stream) {
    const float* inputs = (const float*)d_in[0];
    const float* W      = (const float*)d_in[1];
    const float* bias   = (const float*)d_in[2];
    float* out = (float*)d_out;

    float* c_tab   = (float*)d_ws;           // 65536 f32 = 256 KB
    float* partial = c_tab + I_CAP * J_CAP;  // KCN*32*2048 f32

    const size_t need32 = (size_t)(65536 + 32 * 32 * 2048) * 4;  // 8.64 MB
    const size_t need16 = (size_t)(65536 + 16 * 32 * 2048) * 4;  // 4.45 MB
    int kcn = (ws_size >= need32) ? 32 : (ws_size >= need16) ? 16 : 8;

    caps_softmax_k<<<dim3(256), dim3(256), 0, stream>>>(bias, c_tab);
    if (kcn == 32)
        caps_main_k<16><<<dim3(32 * 32), dim3(256), 0, stream>>>(inputs, W, c_tab, partial);
    else if (kcn == 16)
        caps_main_k<32><<<dim3(16 * 32), dim3(256), 0, stream>>>(inputs, W, c_tab, partial);
    else
        caps_main_k<64><<<dim3(8 * 32), dim3(256), 0, stream>>>(inputs, W, c_tab, partial);
    caps_reduce_squash_k<<<dim3(256), dim3(256), 0, stream>>>(partial, out, kcn);
}

// Round 5
// 39.001 us; speedup vs baseline: 1.5050x; 1.5050x over previous
//
#include <hip/hip_runtime.h>
#include <hip/hip_bf16.h>
#include <math.h>

// inputs: [B=64, I=2048, P=16] f32
// W:      [I=2048, J=32, P=16, D=32] f32
// bias:   [1, I, J, 1, 1] f32
// out:    [B=64, J=32, D=32] f32
#define I_CAP 2048
#define P_DIM 16
#define J_CAP 32
#define D_DIM 32
#define B_SZ  64
#define KCN   32            // i-chunks; grid = KCN * 16 j-pairs = 512 blocks
#define IPB   (I_CAP / KCN) // 64 i per block
#define IPW   (IPB / 4)     // 16 i per wave

typedef __attribute__((ext_vector_type(8)))  short short8_t;
typedef __attribute__((ext_vector_type(16))) float f32x16;

__device__ __forceinline__ short f2bf(float f) {
    __hip_bfloat16 h = __float2bfloat16(f);   // RNE
    return __builtin_bit_cast(short, h);
}

// ---------------- k0: c[i][j] = softmax over j of bias[i][j] ----------------
__global__ __launch_bounds__(256) void caps_softmax_k(const float* __restrict__ bias,
                                                      float* __restrict__ c_tab) {
    int tid = blockIdx.x * 256 + threadIdx.x;   // = i*32 + j
    float x = bias[tid];
    float m = x;
#pragma unroll
    for (int k = 16; k >= 1; k >>= 1) m = fmaxf(m, __shfl_xor(m, k));
    float e = expf(x - m);
    float s = e;
#pragma unroll
    for (int k = 16; k >= 1; k >>= 1) s += __shfl_xor(s, k);
    c_tab[tid] = e / s;
}

// ---------------- k1: main GEMM via bf16 MFMA, j-pair per wave ----------------
// Logical block (kc, jp): 4 waves on disjoint i-subranges, each wave computes
// j0=2*jp and j1=2*jp+1 (4 KB contiguous W per round, 4 MFMA per round).
// XCD-chunked bid swizzle: xcd = bid&7 owns 64 consecutive logical blocks =
// 4 kc groups x 16 jp -> the 16 sharers of each 256KB A-slice are co-XCD (L2-hot).
// B-frag: lane l -> n=d=(l&31), k=p=(l>>5)*8+e   (k-permutation-safe: A uses same map)
// A-frag: lane l -> m=b=(l&31)+32*mf, k=p=(l>>5)*8+e  -> 8 consecutive fp32
// C/D:    b = mf*32 + (reg&3) + 8*(reg>>2) + 4*(l>>5), d = l&31   [m74/m101]
__global__ __launch_bounds__(256, 2) void caps_main_k(const float* __restrict__ inputs,
                                                      const float* __restrict__ W,
                                                      const float* __restrict__ c_tab,
                                                      float* __restrict__ partial) {
    __shared__ float red[4 * 4096];   // 64 KB: [wave][j-pair][64 b][32 d]
    const int t  = threadIdx.x;
    const int l  = t & 63;
    const int wv = t >> 6;

    // chunked XCD swizzle (bijective: 512 % 8 == 0)
    const int orig = blockIdx.x;
    const int wgid = (orig & 7) * 64 + (orig >> 3);
    const int kc = wgid >> 4;          // 0..31
    const int jp = wgid & 15;          // 0..15
    const int j0 = jp * 2;

    const int g  = l >> 5;     // p-half selector (k-group)
    const int dn = l & 31;     // d for B-frag, b for A-frag

    const int i0 = kc * IPB + wv * IPW;

    const float* wlane  = W + (((size_t)(i0 * J_CAP + j0)) << 9) + g * 256 + dn;
    const float* alane0 = inputs + ((size_t)dn << 15) + (size_t)i0 * 16 + g * 8;
    const float* alane1 = alane0 + ((size_t)32 << 15);
    const float* cp     = c_tab + i0 * J_CAP + j0;

    f32x16 accA0 = {};   // j0, b 0..31
    f32x16 accA1 = {};   // j0, b 32..63
    f32x16 accB0 = {};   // j1, b 0..31
    f32x16 accB1 = {};   // j1, b 32..63

#pragma unroll 2
    for (int r = 0; r < IPW; ++r) {
        const float cj0 = cp[r * J_CAP];
        const float cj1 = cp[r * J_CAP + 1];
        float w0buf[8], w1buf[8];
#pragma unroll
        for (int e = 0; e < 8; ++e) {
            w0buf[e] = wlane[(size_t)r * 16384 + e * 32];        // j0 rows
            w1buf[e] = wlane[(size_t)r * 16384 + 512 + e * 32];  // j1 rows (adjacent 2KB)
        }
        float4 a0 = *(const float4*)(alane0 + r * 16);
        float4 a1 = *(const float4*)(alane0 + r * 16 + 4);
        float4 a2 = *(const float4*)(alane1 + r * 16);
        float4 a3 = *(const float4*)(alane1 + r * 16 + 4);

        short8_t bf0, bf1, af0, af1;
#pragma unroll
        for (int e = 0; e < 8; ++e) bf0[e] = f2bf(w0buf[e] * cj0);
#pragma unroll
        for (int e = 0; e < 8; ++e) bf1[e] = f2bf(w1buf[e] * cj1);
        af0[0] = f2bf(a0.x); af0[1] = f2bf(a0.y); af0[2] = f2bf(a0.z); af0[3] = f2bf(a0.w);
        af0[4] = f2bf(a1.x); af0[5] = f2bf(a1.y); af0[6] = f2bf(a1.z); af0[7] = f2bf(a1.w);
        af1[0] = f2bf(a2.x); af1[1] = f2bf(a2.y); af1[2] = f2bf(a2.z); af1[3] = f2bf(a2.w);
        af1[4] = f2bf(a3.x); af1[5] = f2bf(a3.y); af1[6] = f2bf(a3.z); af1[7] = f2bf(a3.w);

        accA0 = __builtin_amdgcn_mfma_f32_32x32x16_bf16(af0, bf0, accA0, 0, 0, 0);
        accA1 = __builtin_amdgcn_mfma_f32_32x32x16_bf16(af1, bf0, accA1, 0, 0, 0);
        accB0 = __builtin_amdgcn_mfma_f32_32x32x16_bf16(af0, bf1, accB0, 0, 0, 0);
        accB1 = __builtin_amdgcn_mfma_f32_32x32x16_bf16(af1, bf1, accB1, 0, 0, 0);
    }

    // ---- epilogue: per-wave C -> LDS (conflict-free), 4-wave sum, partial write --
    {
        float* rw = red + wv * 4096;
#pragma unroll
        for (int reg = 0; reg < 16; ++reg) {
            const int b0 = (reg & 3) + 8 * (reg >> 2) + 4 * g;
            rw[b0 * 32 + dn]               = accA0[reg];
            rw[(b0 + 32) * 32 + dn]        = accA1[reg];
            rw[2048 + b0 * 32 + dn]        = accB0[reg];
            rw[2048 + (b0 + 32) * 32 + dn] = accB1[reg];
        }
    }
    __syncthreads();
    {
        float* dstbase = partial + (size_t)(kc * J_CAP + j0) * 2048;
#pragma unroll
        for (int jj = 0; jj < 2; ++jj) {
#pragma unroll
            for (int s = 0; s < 2; ++s) {
                const int o = jj * 2048 + s * 1024 + t * 4;
                float4 v0 = *(const float4*)(red + o);
                float4 v1 = *(const float4*)(red + 4096 + o);
                float4 v2 = *(const float4*)(red + 8192 + o);
                float4 v3 = *(const float4*)(red + 12288 + o);
                float4 sum = {v0.x + v1.x + v2.x + v3.x,
                              v0.y + v1.y + v2.y + v3.y,
                              v0.z + v1.z + v2.z + v3.z,
                              v0.w + v1.w + v2.w + v3.w};
                *(float4*)(dstbase + o) = sum;   // partial[(kc*32 + j0+jj)*2048 + ...]
            }
        }
    }
}

// ---------------- k2: reduce KCN partials + squash ----------------
// grid = 256 blocks x 256 thr; block -> (j = bid>>3, bgroup = bid&7);
// thread -> (b = bg*8 + t>>5, d = t&31). partial layout: [kc*32+j][b*32+d].
__global__ __launch_bounds__(256) void caps_reduce_squash_k(const float* __restrict__ partial,
                                                            float* __restrict__ out) {
    const int t  = threadIdx.x;
    const int j  = blockIdx.x >> 3;
    const int bg = blockIdx.x & 7;
    const int b  = bg * 8 + (t >> 5);
    const int d  = t & 31;

    const float* src = partial + (size_t)j * 2048 + (size_t)b * 32 + d;
    float v = 0.f;
#pragma unroll 4
    for (int kc = 0; kc < KCN; ++kc)
        v += src[(size_t)kc * J_CAP * 2048];

    float sq = v * v;
#pragma unroll
    for (int k = 16; k >= 1; k >>= 1) sq += __shfl_xor(sq, k);
    // scale = s2 / (1+s2) / sqrt(s2)  (exactly as reference)
    float scale = sq / (1.0f + sq) / sqrtf(sq);
    out[(size_t)b * (J_CAP * D_DIM) + j * D_DIM + d] = v * scale;
}

extern "C" void kernel_launch(void* const* d_in, const int* in_sizes, int n_in,
                              void* d_out, int out_size, void* d_ws, size_t ws_size,
                              hipStream_t stream) {
    const float* inputs = (const float*)d_in[0];
    const float* W      = (const float*)d_in[1];
    const float* bias   = (const float*)d_in[2];
    float* out = (float*)d_out;

    float* c_tab   = (float*)d_ws;           // 65536 f32 = 256 KB
    float* partial = c_tab + I_CAP * J_CAP;  // 32*32*2048 f32 = 8 MB

    caps_softmax_k<<<dim3(256), dim3(256), 0, stream>>>(bias, c_tab);
    caps_main_k<<<dim3(KCN * 16), dim3(256), 0, stream>>>(inputs, W, c_tab, partial);
    caps_reduce_squash_k<<<dim3(256), dim3(256), 0, stream>>>(partial, out);
}